// Round 1
// baseline (342.736 us; speedup 1.0000x reference)
//
#include <hip/hip_runtime.h>

#define B_  8
#define C_  64
#define OC_ 64
#define H_  256
#define W_  256
#define HW_ (H_ * W_)

typedef __attribute__((ext_vector_type(8))) short bf16x8;   // 8 bf16 in 4 VGPRs
typedef __attribute__((ext_vector_type(4))) float f32x4;

__device__ __forceinline__ unsigned short f2bf(float f) {
    unsigned int u = __float_as_uint(f);
    u += 0x7fffu + ((u >> 16) & 1u);     // round-to-nearest-even
    return (unsigned short)(u >> 16);
}

// Round-3 restructure: latency-bound diagnosis (Occ 36%, VALU 9%, MFMA 1%,
// HBM 22% with ideal traffic). One block per (b,h) row, 512 threads:
// thread = (px = tid&255, channel-group cg = tid>>8). Each thread's serial
// load chain is halved (32-ch phase-1 partial dot, 32-ch phase-3 gather),
// and residency doubles: LDS 40KB -> 4 blocks/CU x 8 waves = 32 waves/CU.
__global__ __launch_bounds__(512, 8) void dcn_fused(
    const float* __restrict__ x,
    const float* __restrict__ w_conv,
    const float* __restrict__ w_off,
    const float* __restrict__ b_off,
    const float* __restrict__ w_mask,
    const float* __restrict__ b_mask,
    float* __restrict__ out)
{
    const int g   = blockIdx.x;
    // XCD swizzle: one batch image per XCD -> L2 row reuse for sampling.
    const int row = (g & 7) * (B_ * H_ / 8) + (g >> 3);
    const int b   = row >> 8;
    const int h   = row & (H_ - 1);
    const int px  = threadIdx.x & 255;     // pixel column
    const int cg  = threadIdx.x >> 8;      // channel group 0/1 (32 ch each)

    __shared__ uint4  lds[256 * 8];        // S^T[px][c] bf16, 32 KB, XOR-swizzled
    __shared__ float4 part[2][256];        // phase-1 partial dots, 8 KB

    // ---- Phase 1: partial offset / mask logits over this thread's 32 ch ----
    const float* __restrict__ xp = x + (size_t)b * C_ * HW_ + h * W_ + px;
    const int c0g = cg * 32;
    float oy = 0.f, ox = 0.f, ml = 0.f;
#pragma unroll 16
    for (int c = 0; c < 32; ++c) {
        const float v = xp[(size_t)(c0g + c) * HW_];
        oy = fmaf(w_off[c0g + c],       v, oy);
        ox = fmaf(w_off[C_ + c0g + c],  v, ox);
        ml = fmaf(w_mask[c0g + c],      v, ml);
    }
    part[cg][px] = (float4){oy, ox, ml, 0.f};
    __syncthreads();
    {
        const float4 o2 = part[cg ^ 1][px];
        oy += o2.x + b_off[0];
        ox += o2.y + b_off[1];
        ml += o2.z + b_mask[0];
    }
    const float m = 1.0f / (1.0f + __expf(-ml));

    // ---- Phase 2: bilinear setup (identical numerics to round-2) ----
    const float py  = (float)h + oy;
    const float px_ = (float)px + ox;
    const float y0f = floorf(py);
    const float x0f = floorf(px_);
    const float wy1 = py - y0f, wx1 = px_ - x0f;
    const float wy0 = 1.0f - wy1, wx0 = 1.0f - wx1;
    const int y0 = (int)y0f, x0 = (int)x0f;
    const int y1 = y0 + 1,   x1 = x0 + 1;
    const float vy0 = (y0 >= 0 && y0 < H_) ? 1.0f : 0.0f;
    const float vy1 = (y1 >= 0 && y1 < H_) ? 1.0f : 0.0f;
    const float vx0 = (x0 >= 0 && x0 < W_) ? 1.0f : 0.0f;
    const float vx1 = (x1 >= 0 && x1 < W_) ? 1.0f : 0.0f;
    const int y0c = min(max(y0, 0), H_ - 1);
    const int y1c = min(max(y1, 0), H_ - 1);
    const int x0c = min(max(x0, 0), W_ - 1);
    const int x1c = min(max(x1, 0), W_ - 1);
    const float w00 = wy0 * wx0 * vy0 * vx0 * m;
    const float w01 = wy0 * wx1 * vy0 * vx1 * m;
    const float w10 = wy1 * wx0 * vy1 * vx0 * m;
    const float w11 = wy1 * wx1 * vy1 * vx1 * m;
    const int i00 = y0c * W_ + x0c;
    const int i01 = y0c * W_ + x1c;
    const int i10 = y1c * W_ + x0c;
    const int i11 = y1c * W_ + x1c;

    // ---- Phase 3: masked bilinear sample of this thread's 32 ch -> LDS ----
    const float* __restrict__ xb = x + (size_t)b * C_ * HW_;
#pragma unroll
    for (int jj = 0; jj < 4; ++jj) {
        const int j = cg * 4 + jj;           // 8-channel chunk index 0..7
        float sv[8];
#pragma unroll
        for (int t = 0; t < 8; ++t) {
            const float* __restrict__ xc = xb + (size_t)(8 * j + t) * HW_;
            sv[t] = w00 * xc[i00] + w01 * xc[i01] + w10 * xc[i10] + w11 * xc[i11];
        }
        uint4 u;
        u.x = (unsigned)f2bf(sv[0]) | ((unsigned)f2bf(sv[1]) << 16);
        u.y = (unsigned)f2bf(sv[2]) | ((unsigned)f2bf(sv[3]) << 16);
        u.z = (unsigned)f2bf(sv[4]) | ((unsigned)f2bf(sv[5]) << 16);
        u.w = (unsigned)f2bf(sv[6]) | ((unsigned)f2bf(sv[7]) << 16);
        lds[px * 8 + (j ^ (px & 7))] = u;
    }

    // ---- Phase 4 setup before the barrier: A fragments (w_conv, L2-hot) ----
    const int lane = threadIdx.x & 63;
    const int wv   = threadIdx.x >> 6;       // 0..7
    const int half = wv >> 2;                // which 32-oc half this wave owns
    const int wq   = wv & 3;                 // which 64-px quarter
    const int lrow = lane >> 4;              // 0..3
    const int lcol = lane & 15;

    bf16x8 afrag[2][2];                      // [mtl][kk]: A[m=lcol][k=lrow*8+j]
#pragma unroll
    for (int mtl = 0; mtl < 2; ++mtl) {
#pragma unroll
        for (int kk = 0; kk < 2; ++kk) {
            const int oc = (half * 2 + mtl) * 16 + lcol;
            const int c0 = kk * 32 + lrow * 8;
            const float4* wp = (const float4*)(w_conv + oc * C_ + c0);
            const float4 lo = wp[0];
            const float4 hi = wp[1];
            bf16x8 a;
            a[0] = (short)f2bf(lo.x); a[1] = (short)f2bf(lo.y);
            a[2] = (short)f2bf(lo.z); a[3] = (short)f2bf(lo.w);
            a[4] = (short)f2bf(hi.x); a[5] = (short)f2bf(hi.y);
            a[6] = (short)f2bf(hi.z); a[7] = (short)f2bf(hi.w);
            afrag[mtl][kk] = a;
        }
    }

    __syncthreads();

    // ---- Phase 4: GEMM via mfma_f32_16x16x32_bf16, one half per wave ----
    f32x4 acc[2][4];
#pragma unroll
    for (int mtl = 0; mtl < 2; ++mtl)
#pragma unroll
        for (int nt = 0; nt < 4; ++nt)
            acc[mtl][nt] = (f32x4){0.f, 0.f, 0.f, 0.f};

#pragma unroll
    for (int nt = 0; nt < 4; ++nt) {
        const int p2 = wq * 64 + nt * 16 + lcol;     // B: n = lcol
#pragma unroll
        for (int kk = 0; kk < 2; ++kk) {
            const int cblk = kk * 4 + lrow;          // B: k = lrow*8+j
            union { uint4 u; bf16x8 v; } bb;
            bb.u = lds[p2 * 8 + (cblk ^ (p2 & 7))];
#pragma unroll
            for (int mtl = 0; mtl < 2; ++mtl)
                acc[mtl][nt] = __builtin_amdgcn_mfma_f32_16x16x32_bf16(
                    afrag[mtl][kk], bb.v, acc[mtl][nt], 0, 0, 0);
        }
    }

    // ---- Epilogue: C/D layout col=lane&15, row=(lane>>4)*4+r ----
    // Nontemporal: out is write-once, keep x resident in L3 across dispatches.
    float* __restrict__ ob = out + (size_t)b * OC_ * HW_ + h * W_;
#pragma unroll
    for (int mtl = 0; mtl < 2; ++mtl) {
        const int ocb = (half * 2 + mtl) * 16 + lrow * 4;
#pragma unroll
        for (int nt = 0; nt < 4; ++nt) {
            const int p2 = wq * 64 + nt * 16 + lcol;
            const f32x4 a = acc[mtl][nt];
#pragma unroll
            for (int r = 0; r < 4; ++r)
                __builtin_nontemporal_store(a[r], &ob[(size_t)(ocb + r) * HW_ + p2]);
        }
    }
}

extern "C" void kernel_launch(void* const* d_in, const int* in_sizes, int n_in,
                              void* d_out, int out_size, void* d_ws, size_t ws_size,
                              hipStream_t stream) {
    const float* x      = (const float*)d_in[0];
    const float* w_conv = (const float*)d_in[1];
    const float* w_off  = (const float*)d_in[2];
    const float* b_off  = (const float*)d_in[3];
    const float* w_mask = (const float*)d_in[4];
    const float* b_mask = (const float*)d_in[5];
    float* out = (float*)d_out;

    dcn_fused<<<dim3(B_ * H_), dim3(512), 0, stream>>>(
        x, w_conv, w_off, b_off, w_mask, b_mask, out);
}

// Round 2
// 326.015 us; speedup vs baseline: 1.0513x; 1.0513x over previous
//
#include <hip/hip_runtime.h>

#define B_  8
#define C_  64
#define OC_ 64
#define H_  256
#define W_  256
#define HW_ (H_ * W_)

typedef __attribute__((ext_vector_type(8))) short bf16x8;   // 8 bf16 in 4 VGPRs
typedef __attribute__((ext_vector_type(4))) float f32x4;

__device__ __forceinline__ unsigned short f2bf(float f) {
    unsigned int u = __float_as_uint(f);
    u += 0x7fffu + ((u >> 16) & 1u);     // round-to-nearest-even
    return (unsigned short)(u >> 16);
}

// Round-4: latency-bound diagnosis persists (VALU 12%, MFMA 1%, HBM 22%,
// traffic ideal). Round-3 lesson: occupancy alone doesn't help if VGPR
// collapses to 32 (few loads in flight). This round maximizes the MLP
// product: (512,6) -> VGPR cap ~85, 24 waves/CU, and phase-1/phase-3 loads
// are explicitly batched into arrays (32 in flight) before any FMA.
// Nontemporal stores reverted (round-3: +70MB partial-line write traffic).
__global__ __launch_bounds__(512, 6) void dcn_fused(
    const float* __restrict__ x,
    const float* __restrict__ w_conv,
    const float* __restrict__ w_off,
    const float* __restrict__ b_off,
    const float* __restrict__ w_mask,
    const float* __restrict__ b_mask,
    float* __restrict__ out)
{
    const int g   = blockIdx.x;
    // XCD swizzle: one batch image per XCD -> L2 row reuse for sampling.
    const int row = (g & 7) * (B_ * H_ / 8) + (g >> 3);
    const int b   = row >> 8;
    const int h   = row & (H_ - 1);
    const int px  = threadIdx.x & 255;     // pixel column
    const int cg  = threadIdx.x >> 8;      // channel group 0/1 (32 ch each)

    __shared__ uint4  lds[256 * 8];        // S^T[px][c] bf16, 32 KB, XOR-swizzled
    __shared__ float4 part[2][256];        // phase-1 partial dots, 8 KB

    // ---- Phase 1: partial offset/mask logits over this thread's 32 ch ----
    // Loads batched 16-at-a-time to keep deep MLP.
    const float* __restrict__ xp = x + (size_t)b * C_ * HW_ + h * W_ + px;
    const int c0g = cg * 32;
    float oy = 0.f, ox = 0.f, ml = 0.f;
#pragma unroll
    for (int hh = 0; hh < 2; ++hh) {
        float vv[16];
#pragma unroll
        for (int c = 0; c < 16; ++c)
            vv[c] = xp[(size_t)(c0g + hh * 16 + c) * HW_];
#pragma unroll
        for (int c = 0; c < 16; ++c) {
            const int cc = c0g + hh * 16 + c;
            oy = fmaf(w_off[cc],      vv[c], oy);
            ox = fmaf(w_off[C_ + cc], vv[c], ox);
            ml = fmaf(w_mask[cc],     vv[c], ml);
        }
    }
    part[cg][px] = (float4){oy, ox, ml, 0.f};
    __syncthreads();
    {
        const float4 o2 = part[cg ^ 1][px];
        oy += o2.x + b_off[0];
        ox += o2.y + b_off[1];
        ml += o2.z + b_mask[0];
    }
    const float m = 1.0f / (1.0f + __expf(-ml));

    // ---- Phase 2: bilinear setup (identical numerics) ----
    const float py  = (float)h + oy;
    const float px_ = (float)px + ox;
    const float y0f = floorf(py);
    const float x0f = floorf(px_);
    const float wy1 = py - y0f, wx1 = px_ - x0f;
    const float wy0 = 1.0f - wy1, wx0 = 1.0f - wx1;
    const int y0 = (int)y0f, x0 = (int)x0f;
    const int y1 = y0 + 1,   x1 = x0 + 1;
    const float vy0 = (y0 >= 0 && y0 < H_) ? 1.0f : 0.0f;
    const float vy1 = (y1 >= 0 && y1 < H_) ? 1.0f : 0.0f;
    const float vx0 = (x0 >= 0 && x0 < W_) ? 1.0f : 0.0f;
    const float vx1 = (x1 >= 0 && x1 < W_) ? 1.0f : 0.0f;
    const int y0c = min(max(y0, 0), H_ - 1);
    const int y1c = min(max(y1, 0), H_ - 1);
    const int x0c = min(max(x0, 0), W_ - 1);
    const int x1c = min(max(x1, 0), W_ - 1);
    const float w00 = wy0 * wx0 * vy0 * vx0 * m;
    const float w01 = wy0 * wx1 * vy0 * vx1 * m;
    const float w10 = wy1 * wx0 * vy1 * vx0 * m;
    const float w11 = wy1 * wx1 * vy1 * vx1 * m;
    const int i00 = y0c * W_ + x0c;
    const int i01 = y0c * W_ + x1c;
    const int i10 = y1c * W_ + x0c;
    const int i11 = y1c * W_ + x1c;

    // ---- Phase 3: masked bilinear sample of this thread's 32 ch -> LDS ----
    // All 32 corner loads of an 8-ch chunk issued before any FMA (MLP=32).
    const float* __restrict__ xb = x + (size_t)b * C_ * HW_;
#pragma unroll
    for (int jj = 0; jj < 4; ++jj) {
        const int j = cg * 4 + jj;           // 8-channel chunk index 0..7
        const float* __restrict__ xc0 = xb + (size_t)(8 * j) * HW_;
        float c00[8], c01[8], c10[8], c11[8];
#pragma unroll
        for (int t = 0; t < 8; ++t) {
            const float* __restrict__ xc = xc0 + (size_t)t * HW_;
            c00[t] = xc[i00];
            c01[t] = xc[i01];
            c10[t] = xc[i10];
            c11[t] = xc[i11];
        }
        float sv[8];
#pragma unroll
        for (int t = 0; t < 8; ++t)
            sv[t] = w00 * c00[t] + w01 * c01[t] + w10 * c10[t] + w11 * c11[t];
        uint4 u;
        u.x = (unsigned)f2bf(sv[0]) | ((unsigned)f2bf(sv[1]) << 16);
        u.y = (unsigned)f2bf(sv[2]) | ((unsigned)f2bf(sv[3]) << 16);
        u.z = (unsigned)f2bf(sv[4]) | ((unsigned)f2bf(sv[5]) << 16);
        u.w = (unsigned)f2bf(sv[6]) | ((unsigned)f2bf(sv[7]) << 16);
        lds[px * 8 + (j ^ (px & 7))] = u;
    }

    // ---- Phase 4 setup before the barrier: A fragments (w_conv, L2-hot) ----
    const int lane = threadIdx.x & 63;
    const int wv   = threadIdx.x >> 6;       // 0..7
    const int half = wv >> 2;                // which 32-oc half this wave owns
    const int wq   = wv & 3;                 // which 64-px quarter
    const int lrow = lane >> 4;              // 0..3
    const int lcol = lane & 15;

    bf16x8 afrag[2][2];                      // [mtl][kk]: A[m=lcol][k=lrow*8+j]
#pragma unroll
    for (int mtl = 0; mtl < 2; ++mtl) {
#pragma unroll
        for (int kk = 0; kk < 2; ++kk) {
            const int oc = (half * 2 + mtl) * 16 + lcol;
            const int c0 = kk * 32 + lrow * 8;
            const float4* wp = (const float4*)(w_conv + oc * C_ + c0);
            const float4 lo = wp[0];
            const float4 hi = wp[1];
            bf16x8 a;
            a[0] = (short)f2bf(lo.x); a[1] = (short)f2bf(lo.y);
            a[2] = (short)f2bf(lo.z); a[3] = (short)f2bf(lo.w);
            a[4] = (short)f2bf(hi.x); a[5] = (short)f2bf(hi.y);
            a[6] = (short)f2bf(hi.z); a[7] = (short)f2bf(hi.w);
            afrag[mtl][kk] = a;
        }
    }

    __syncthreads();

    // ---- Phase 4: GEMM via mfma_f32_16x16x32_bf16, one half per wave ----
    f32x4 acc[2][4];
#pragma unroll
    for (int mtl = 0; mtl < 2; ++mtl)
#pragma unroll
        for (int nt = 0; nt < 4; ++nt)
            acc[mtl][nt] = (f32x4){0.f, 0.f, 0.f, 0.f};

#pragma unroll
    for (int nt = 0; nt < 4; ++nt) {
        const int p2 = wq * 64 + nt * 16 + lcol;     // B: n = lcol
#pragma unroll
        for (int kk = 0; kk < 2; ++kk) {
            const int cblk = kk * 4 + lrow;          // B: k = lrow*8+j
            union { uint4 u; bf16x8 v; } bb;
            bb.u = lds[p2 * 8 + (cblk ^ (p2 & 7))];
#pragma unroll
            for (int mtl = 0; mtl < 2; ++mtl)
                acc[mtl][nt] = __builtin_amdgcn_mfma_f32_16x16x32_bf16(
                    afrag[mtl][kk], bb.v, acc[mtl][nt], 0, 0, 0);
        }
    }

    // ---- Epilogue: C/D layout col=lane&15, row=(lane>>4)*4+r ----
    float* __restrict__ ob = out + (size_t)b * OC_ * HW_ + h * W_;
#pragma unroll
    for (int mtl = 0; mtl < 2; ++mtl) {
        const int ocb = (half * 2 + mtl) * 16 + lrow * 4;
#pragma unroll
        for (int nt = 0; nt < 4; ++nt) {
            const int p2 = wq * 64 + nt * 16 + lcol;
            const f32x4 a = acc[mtl][nt];
#pragma unroll
            for (int r = 0; r < 4; ++r)
                ob[(size_t)(ocb + r) * HW_ + p2] = a[r];
        }
    }
}

extern "C" void kernel_launch(void* const* d_in, const int* in_sizes, int n_in,
                              void* d_out, int out_size, void* d_ws, size_t ws_size,
                              hipStream_t stream) {
    const float* x      = (const float*)d_in[0];
    const float* w_conv = (const float*)d_in[1];
    const float* w_off  = (const float*)d_in[2];
    const float* b_off  = (const float*)d_in[3];
    const float* w_mask = (const float*)d_in[4];
    const float* b_mask = (const float*)d_in[5];
    float* out = (float*)d_out;

    dcn_fused<<<dim3(B_ * H_), dim3(512), 0, stream>>>(
        x, w_conv, w_off, b_off, w_mask, b_mask, out);
}

// Round 3
// 305.585 us; speedup vs baseline: 1.1216x; 1.0669x over previous
//
#include <hip/hip_runtime.h>

#define B_  8
#define C_  64
#define OC_ 64
#define H_  256
#define W_  256
#define HW_ (H_ * W_)

typedef __attribute__((ext_vector_type(8))) short bf16x8;   // 8 bf16 in 4 VGPRs
typedef __attribute__((ext_vector_type(4))) float f32x4;
typedef _Float16 h2v  __attribute__((ext_vector_type(2)));  // packed fp16 pair
typedef _Float16 h8v  __attribute__((ext_vector_type(8)));  // MFMA f16 A/B frag

__device__ __forceinline__ unsigned short f2bf(float f) {
    unsigned int u = __float_as_uint(f);
    u += 0x7fffu + ((u >> 16) & 1u);     // round-to-nearest-even
    return (unsigned short)(u >> 16);
}

// ============================================================================
// Round-5 restructure. Diagnosis: rounds 0-2 are L2/L3-transaction-bound:
// gathers with per-lane y-jitter touch ~15 lines/wave-load (~2 GB of L2/L3
// traffic = 163 us at ~12 TB/s), and no scheduling knob changed it.
// Fix the LAYOUT: kernel 1 builds an fp16 HWC copy of x (one corner = 32ch
// = exactly one 64B line) + precomputed bilinear weights/indices; kernel 2
// gathers line-perfectly and runs the GEMM in f16 MFMA.
// ============================================================================

// ---------------------------------------------------------------------------
// Kernel 1: per (b,y) row: coalesced x read -> LDS transpose -> fp16 HWC row
// + offset/mask dots -> folded bilinear weights + byte indices.
// LDS row layout: [px][72 halfs], data in 8 uint4 chunks (8ch each), chunk j
// stored at (j ^ (px&7)) -> conflict-free writes, <=4-way reads.
// ---------------------------------------------------------------------------
__global__ __launch_bounds__(512, 8) void dcn_prep(
    const float* __restrict__ x,
    const float* __restrict__ w_off,
    const float* __restrict__ b_off,
    const float* __restrict__ w_mask,
    const float* __restrict__ b_mask,
    _Float16* __restrict__ x16,      // [B][H][W][C] fp16
    float4* __restrict__ pw,         // [B*HW] w00,w01,w10,w11 (mask folded)
    int4*  __restrict__ pi)          // [B*HW] corner byte offsets in image
{
    const int g   = blockIdx.x;
    const int row = (g & 7) * (B_ * H_ / 8) + (g >> 3);
    const int b   = row >> 8;
    const int y   = row & (H_ - 1);
    const int t   = threadIdx.x;

    __shared__ _Float16 lt[256 * 72];     // 36 KB
    __shared__ float4   part[2][256];     // 8 KB

    // ---- Phase A: load 2 channel-rows x 16 px, pack pairs into LDS ----
    {
        const int c2  = t & 31;           // channel pair 0..31  (c = 2*c2)
        const int gq  = t >> 5;           // px group 0..15
        const int pxa = gq * 16;
        const float* __restrict__ xr0 = x + ((size_t)b * C_ + 2 * c2) * HW_ + y * W_ + pxa;
        const float* __restrict__ xr1 = xr0 + HW_;
        float4 v0[4], v1[4];
#pragma unroll
        for (int q = 0; q < 4; ++q) {
            v0[q] = ((const float4*)xr0)[q];
            v1[q] = ((const float4*)xr1)[q];
        }
#pragma unroll
        for (int q = 0; q < 4; ++q) {
            const float* a0 = (const float*)&v0[q];
            const float* a1 = (const float*)&v1[q];
#pragma unroll
            for (int e = 0; e < 4; ++e) {
                const int pxw = pxa + q * 4 + e;
                h2v pk;
                pk[0] = (_Float16)a0[e];
                pk[1] = (_Float16)a1[e];
                *(h2v*)(lt + pxw * 72 + ((c2 >> 2) ^ (pxw & 7)) * 8 + (c2 & 3) * 2) = pk;
            }
        }
    }
    __syncthreads();

    // ---- Phase B: write fp16 HWC row (coalesced 64B per thread) ----
    {
        const int pxb = t >> 1, h2i = t & 1;
        uint4* dst = (uint4*)((char*)x16 + ((size_t)b << 23)
                              + (size_t)(y * W_ + pxb) * 128 + h2i * 64);
#pragma unroll
        for (int k = 0; k < 4; ++k) {
            const int j = h2i * 4 + k;
            dst[k] = *(const uint4*)(lt + pxb * 72 + (j ^ (pxb & 7)) * 8);
        }
    }

    // ---- Phase C: offset/mask dot + bilinear setup ----
    {
        const int pxc = t & 255, cg = t >> 8;
        float oy = 0.f, ox = 0.f, ml = 0.f;
#pragma unroll
        for (int k = 0; k < 4; ++k) {
            const int j = cg * 4 + k;
            union { uint4 u; _Float16 hv[8]; } blk;
            blk.u = *(const uint4*)(lt + pxc * 72 + (j ^ (pxc & 7)) * 8);
#pragma unroll
            for (int e = 0; e < 8; ++e) {
                const float v = (float)blk.hv[e];
                const int c = j * 8 + e;
                oy = fmaf(w_off[c],      v, oy);
                ox = fmaf(w_off[C_ + c], v, ox);
                ml = fmaf(w_mask[c],     v, ml);
            }
        }
        part[cg][pxc] = (float4){oy, ox, ml, 0.f};
        __syncthreads();
        if (cg == 0) {
            const float4 o2 = part[1][pxc];
            oy += o2.x + b_off[0];
            ox += o2.y + b_off[1];
            ml += o2.z + b_mask[0];
            const float m = 1.0f / (1.0f + __expf(-ml));

            const float py  = (float)y + oy;
            const float px_ = (float)pxc + ox;
            const float y0f = floorf(py);
            const float x0f = floorf(px_);
            const float wy1 = py - y0f, wx1 = px_ - x0f;
            const float wy0 = 1.0f - wy1, wx0 = 1.0f - wx1;
            const int y0 = (int)y0f, x0 = (int)x0f;
            const int y1 = y0 + 1,   x1 = x0 + 1;
            const float vy0 = (y0 >= 0 && y0 < H_) ? 1.0f : 0.0f;
            const float vy1 = (y1 >= 0 && y1 < H_) ? 1.0f : 0.0f;
            const float vx0 = (x0 >= 0 && x0 < W_) ? 1.0f : 0.0f;
            const float vx1 = (x1 >= 0 && x1 < W_) ? 1.0f : 0.0f;
            const int y0c = min(max(y0, 0), H_ - 1);
            const int y1c = min(max(y1, 0), H_ - 1);
            const int x0c = min(max(x0, 0), W_ - 1);
            const int x1c = min(max(x1, 0), W_ - 1);
            const int pidx = row * W_ + pxc;
            pw[pidx] = (float4){wy0 * wx0 * vy0 * vx0 * m,
                                wy0 * wx1 * vy0 * vx1 * m,
                                wy1 * wx0 * vy1 * vx0 * m,
                                wy1 * wx1 * vy1 * vx1 * m};
            pi[pidx] = (int4){(y0c * W_ + x0c) * 128,
                              (y0c * W_ + x1c) * 128,
                              (y1c * W_ + x0c) * 128,
                              (y1c * W_ + x1c) * 128};
        }
    }
}

// ---------------------------------------------------------------------------
// Kernel 2: line-perfect gathers from HWC fp16 + packed-f16 interp + f16 MFMA.
// ---------------------------------------------------------------------------
__global__ __launch_bounds__(512, 6) void dcn_main(
    const _Float16* __restrict__ x16,
    const float4* __restrict__ pw,
    const int4*  __restrict__ pi,
    const float* __restrict__ w_conv,
    float* __restrict__ out)
{
    const int g   = blockIdx.x;
    const int row = (g & 7) * (B_ * H_ / 8) + (g >> 3);
    const int b   = row >> 8;
    const int h   = row & (H_ - 1);
    const int px  = threadIdx.x & 255;
    const int cg  = threadIdx.x >> 8;

    __shared__ uint4 lds[256 * 8];   // S^T[px][c] fp16, 32 KB, XOR-swizzled

    const int pidx = row * W_ + px;
    const float4 wv = pw[pidx];
    const int4   iv = pi[pidx];
    const char* base = (const char*)x16 + ((size_t)b << 23) + cg * 64;

    h2v W00, W01, W10, W11;
    W00[0] = W00[1] = (_Float16)wv.x;
    W01[0] = W01[1] = (_Float16)wv.y;
    W10[0] = W10[1] = (_Float16)wv.z;
    W11[0] = W11[1] = (_Float16)wv.w;

    // Two batches of (2 chunks x 4 corners) = 8 outstanding 16B gathers each.
#pragma unroll
    for (int kk = 0; kk < 2; ++kk) {
        uint4 c00[2], c01[2], c10[2], c11[2];
#pragma unroll
        for (int k = 0; k < 2; ++k) {
            const int off = (kk * 2 + k) * 16;
            c00[k] = *(const uint4*)(base + iv.x + off);
            c01[k] = *(const uint4*)(base + iv.y + off);
            c10[k] = *(const uint4*)(base + iv.z + off);
            c11[k] = *(const uint4*)(base + iv.w + off);
        }
#pragma unroll
        for (int k = 0; k < 2; ++k) {
            union { uint4 u; h2v p[4]; } a0, a1, a2, a3, s;
            a0.u = c00[k]; a1.u = c01[k]; a2.u = c10[k]; a3.u = c11[k];
#pragma unroll
            for (int w2 = 0; w2 < 4; ++w2)
                s.p[w2] = W00 * a0.p[w2] + W01 * a1.p[w2]
                        + W10 * a2.p[w2] + W11 * a3.p[w2];
            const int j = cg * 4 + kk * 2 + k;
            lds[px * 8 + (j ^ (px & 7))] = s.u;
        }
    }

    // ---- A fragments (w_conv f32 -> f16, L2-hot) before the barrier ----
    const int lane = threadIdx.x & 63;
    const int wv_  = threadIdx.x >> 6;       // 0..7
    const int half = wv_ >> 2;               // 32-oc half
    const int wq   = wv_ & 3;                // 64-px quarter
    const int lrow = lane >> 4;              // 0..3
    const int lcol = lane & 15;

    h8v afrag[2][2];
#pragma unroll
    for (int mtl = 0; mtl < 2; ++mtl) {
#pragma unroll
        for (int kk = 0; kk < 2; ++kk) {
            const int oc = (half * 2 + mtl) * 16 + lcol;
            const int c0 = kk * 32 + lrow * 8;
            const float4* wp = (const float4*)(w_conv + oc * C_ + c0);
            const float4 lo = wp[0];
            const float4 hi = wp[1];
            h8v a;
            a[0] = (_Float16)lo.x; a[1] = (_Float16)lo.y;
            a[2] = (_Float16)lo.z; a[3] = (_Float16)lo.w;
            a[4] = (_Float16)hi.x; a[5] = (_Float16)hi.y;
            a[6] = (_Float16)hi.z; a[7] = (_Float16)hi.w;
            afrag[mtl][kk] = a;
        }
    }

    __syncthreads();

    // ---- GEMM via mfma_f32_16x16x32_f16, one 32-oc half per wave ----
    f32x4 acc[2][4];
#pragma unroll
    for (int mtl = 0; mtl < 2; ++mtl)
#pragma unroll
        for (int nt = 0; nt < 4; ++nt)
            acc[mtl][nt] = (f32x4){0.f, 0.f, 0.f, 0.f};

#pragma unroll
    for (int nt = 0; nt < 4; ++nt) {
        const int p2 = wq * 64 + nt * 16 + lcol;     // B: n = lcol
#pragma unroll
        for (int kk = 0; kk < 2; ++kk) {
            const int cblk = kk * 4 + lrow;          // B: k = lrow*8+j
            union { uint4 u; h8v v; } bb;
            bb.u = lds[p2 * 8 + (cblk ^ (p2 & 7))];
#pragma unroll
            for (int mtl = 0; mtl < 2; ++mtl)
                acc[mtl][nt] = __builtin_amdgcn_mfma_f32_16x16x32_f16(
                    afrag[mtl][kk], bb.v, acc[mtl][nt], 0, 0, 0);
        }
    }

    // ---- Epilogue: C/D layout col=lane&15, row=(lane>>4)*4+r ----
    float* __restrict__ ob = out + (size_t)b * OC_ * HW_ + h * W_;
#pragma unroll
    for (int mtl = 0; mtl < 2; ++mtl) {
        const int ocb = (half * 2 + mtl) * 16 + lrow * 4;
#pragma unroll
        for (int nt = 0; nt < 4; ++nt) {
            const int p2 = wq * 64 + nt * 16 + lcol;
            const f32x4 a = acc[mtl][nt];
#pragma unroll
            for (int r = 0; r < 4; ++r)
                ob[(size_t)(ocb + r) * HW_ + p2] = a[r];
        }
    }
}

// ---------------------------------------------------------------------------
// Fallback (ws too small): round-2 fused kernel, proven correct.
// ---------------------------------------------------------------------------
__global__ __launch_bounds__(512, 6) void dcn_fused(
    const float* __restrict__ x,
    const float* __restrict__ w_conv,
    const float* __restrict__ w_off,
    const float* __restrict__ b_off,
    const float* __restrict__ w_mask,
    const float* __restrict__ b_mask,
    float* __restrict__ out)
{
    const int g   = blockIdx.x;
    const int row = (g & 7) * (B_ * H_ / 8) + (g >> 3);
    const int b   = row >> 8;
    const int h   = row & (H_ - 1);
    const int px  = threadIdx.x & 255;
    const int cg  = threadIdx.x >> 8;

    __shared__ uint4  lds[256 * 8];
    __shared__ float4 part[2][256];

    const float* __restrict__ xp = x + (size_t)b * C_ * HW_ + h * W_ + px;
    const int c0g = cg * 32;
    float oy = 0.f, ox = 0.f, ml = 0.f;
#pragma unroll
    for (int hh = 0; hh < 2; ++hh) {
        float vv[16];
#pragma unroll
        for (int c = 0; c < 16; ++c)
            vv[c] = xp[(size_t)(c0g + hh * 16 + c) * HW_];
#pragma unroll
        for (int c = 0; c < 16; ++c) {
            const int cc = c0g + hh * 16 + c;
            oy = fmaf(w_off[cc],      vv[c], oy);
            ox = fmaf(w_off[C_ + cc], vv[c], ox);
            ml = fmaf(w_mask[cc],     vv[c], ml);
        }
    }
    part[cg][px] = (float4){oy, ox, ml, 0.f};
    __syncthreads();
    {
        const float4 o2 = part[cg ^ 1][px];
        oy += o2.x + b_off[0];
        ox += o2.y + b_off[1];
        ml += o2.z + b_mask[0];
    }
    const float m = 1.0f / (1.0f + __expf(-ml));

    const float py  = (float)h + oy;
    const float px_ = (float)px + ox;
    const float y0f = floorf(py);
    const float x0f = floorf(px_);
    const float wy1 = py - y0f, wx1 = px_ - x0f;
    const float wy0 = 1.0f - wy1, wx0 = 1.0f - wx1;
    const int y0 = (int)y0f, x0 = (int)x0f;
    const int y1 = y0 + 1,   x1 = x0 + 1;
    const float vy0 = (y0 >= 0 && y0 < H_) ? 1.0f : 0.0f;
    const float vy1 = (y1 >= 0 && y1 < H_) ? 1.0f : 0.0f;
    const float vx0 = (x0 >= 0 && x0 < W_) ? 1.0f : 0.0f;
    const float vx1 = (x1 >= 0 && x1 < W_) ? 1.0f : 0.0f;
    const int y0c = min(max(y0, 0), H_ - 1);
    const int y1c = min(max(y1, 0), H_ - 1);
    const int x0c = min(max(x0, 0), W_ - 1);
    const int x1c = min(max(x1, 0), W_ - 1);
    const float w00 = wy0 * wx0 * vy0 * vx0 * m;
    const float w01 = wy0 * wx1 * vy0 * vx1 * m;
    const float w10 = wy1 * wx0 * vy1 * vx0 * m;
    const float w11 = wy1 * wx1 * vy1 * vx1 * m;
    const int i00 = y0c * W_ + x0c;
    const int i01 = y0c * W_ + x1c;
    const int i10 = y1c * W_ + x0c;
    const int i11 = y1c * W_ + x1c;

    const float* __restrict__ xb = x + (size_t)b * C_ * HW_;
#pragma unroll
    for (int jj = 0; jj < 4; ++jj) {
        const int j = cg * 4 + jj;
        const float* __restrict__ xc0 = xb + (size_t)(8 * j) * HW_;
        float c00[8], c01[8], c10[8], c11[8];
#pragma unroll
        for (int t = 0; t < 8; ++t) {
            const float* __restrict__ xc = xc0 + (size_t)t * HW_;
            c00[t] = xc[i00];
            c01[t] = xc[i01];
            c10[t] = xc[i10];
            c11[t] = xc[i11];
        }
        float sv[8];
#pragma unroll
        for (int t = 0; t < 8; ++t)
            sv[t] = w00 * c00[t] + w01 * c01[t] + w10 * c10[t] + w11 * c11[t];
        uint4 u;
        u.x = (unsigned)f2bf(sv[0]) | ((unsigned)f2bf(sv[1]) << 16);
        u.y = (unsigned)f2bf(sv[2]) | ((unsigned)f2bf(sv[3]) << 16);
        u.z = (unsigned)f2bf(sv[4]) | ((unsigned)f2bf(sv[5]) << 16);
        u.w = (unsigned)f2bf(sv[6]) | ((unsigned)f2bf(sv[7]) << 16);
        lds[px * 8 + (j ^ (px & 7))] = u;
    }

    const int lane = threadIdx.x & 63;
    const int wv   = threadIdx.x >> 6;
    const int half = wv >> 2;
    const int wq   = wv & 3;
    const int lrow = lane >> 4;
    const int lcol = lane & 15;

    bf16x8 afrag[2][2];
#pragma unroll
    for (int mtl = 0; mtl < 2; ++mtl) {
#pragma unroll
        for (int kk = 0; kk < 2; ++kk) {
            const int oc = (half * 2 + mtl) * 16 + lcol;
            const int c0 = kk * 32 + lrow * 8;
            const float4* wp = (const float4*)(w_conv + oc * C_ + c0);
            const float4 lo = wp[0];
            const float4 hi = wp[1];
            bf16x8 a;
            a[0] = (short)f2bf(lo.x); a[1] = (short)f2bf(lo.y);
            a[2] = (short)f2bf(lo.z); a[3] = (short)f2bf(lo.w);
            a[4] = (short)f2bf(hi.x); a[5] = (short)f2bf(hi.y);
            a[6] = (short)f2bf(hi.z); a[7] = (short)f2bf(hi.w);
            afrag[mtl][kk] = a;
        }
    }

    __syncthreads();

    f32x4 acc[2][4];
#pragma unroll
    for (int mtl = 0; mtl < 2; ++mtl)
#pragma unroll
        for (int nt = 0; nt < 4; ++nt)
            acc[mtl][nt] = (f32x4){0.f, 0.f, 0.f, 0.f};

#pragma unroll
    for (int nt = 0; nt < 4; ++nt) {
        const int p2 = wq * 64 + nt * 16 + lcol;
#pragma unroll
        for (int kk = 0; kk < 2; ++kk) {
            const int cblk = kk * 4 + lrow;
            union { uint4 u; bf16x8 v; } bb;
            bb.u = lds[p2 * 8 + (cblk ^ (p2 & 7))];
#pragma unroll
            for (int mtl = 0; mtl < 2; ++mtl)
                acc[mtl][nt] = __builtin_amdgcn_mfma_f32_16x16x32_bf16(
                    afrag[mtl][kk], bb.v, acc[mtl][nt], 0, 0, 0);
        }
    }

    float* __restrict__ ob = out + (size_t)b * OC_ * HW_ + h * W_;
#pragma unroll
    for (int mtl = 0; mtl < 2; ++mtl) {
        const int ocb = (half * 2 + mtl) * 16 + lrow * 4;
#pragma unroll
        for (int nt = 0; nt < 4; ++nt) {
            const int p2 = wq * 64 + nt * 16 + lcol;
            const f32x4 a = acc[mtl][nt];
#pragma unroll
            for (int r = 0; r < 4; ++r)
                ob[(size_t)(ocb + r) * HW_ + p2] = a[r];
        }
    }
}

extern "C" void kernel_launch(void* const* d_in, const int* in_sizes, int n_in,
                              void* d_out, int out_size, void* d_ws, size_t ws_size,
                              hipStream_t stream) {
    const float* x      = (const float*)d_in[0];
    const float* w_conv = (const float*)d_in[1];
    const float* w_off  = (const float*)d_in[2];
    const float* b_off  = (const float*)d_in[3];
    const float* w_mask = (const float*)d_in[4];
    const float* b_mask = (const float*)d_in[5];
    float* out = (float*)d_out;

    const size_t x16_bytes = (size_t)B_ * HW_ * C_ * 2;          // 64 MiB
    const size_t pw_bytes  = (size_t)B_ * HW_ * sizeof(float4);  // 8 MiB
    const size_t pi_bytes  = (size_t)B_ * HW_ * sizeof(int4);    // 8 MiB

    if (ws_size >= x16_bytes + pw_bytes + pi_bytes) {
        char* wsb = (char*)d_ws;
        _Float16* x16 = (_Float16*)wsb;
        float4*   pw  = (float4*)(wsb + x16_bytes);
        int4*     pi  = (int4*)(wsb + x16_bytes + pw_bytes);

        dcn_prep<<<dim3(B_ * H_), dim3(512), 0, stream>>>(
            x, w_off, b_off, w_mask, b_mask, x16, pw, pi);
        dcn_main<<<dim3(B_ * H_), dim3(512), 0, stream>>>(
            x16, pw, pi, w_conv, out);
    } else {
        dcn_fused<<<dim3(B_ * H_), dim3(512), 0, stream>>>(
            x, w_conv, w_off, b_off, w_mask, b_mask, out);
    }
}

// Round 4
// 300.534 us; speedup vs baseline: 1.1404x; 1.0168x over previous
//
#include <hip/hip_runtime.h>

#define B_  8
#define C_  64
#define OC_ 64
#define H_  256
#define W_  256
#define HW_ (H_ * W_)

typedef __attribute__((ext_vector_type(4))) float f32x4;
typedef _Float16 h2v __attribute__((ext_vector_type(2)));  // packed fp16 pair
typedef _Float16 h8v __attribute__((ext_vector_type(8)));  // MFMA f16 A/B frag

// chunk-slot swizzle: spreads the 8 16B channel-chunks of a pixel across
// banks keyed by pixel, bijective per px (XOR involution).
__device__ __forceinline__ int swz(int p) { return (p ^ (p >> 3)) & 7; }

// ============================================================================
// Round-6: single fused kernel, NO workspace. Round-3 lesson: any d_ws use
// triggers a 512 MiB poison-fill per timed iteration (~80 us) that erased the
// two-kernel win (prep+main were ~72 us combined). This kernel keeps the
// channel-contiguous fp16 layout but builds it in LDS per block:
//   Phase A: stage rows clamp(h-1..h+1) x 64ch as fp16 chunks (96 KB LDS).
//   Phase B: offset/mask dot read from the staged row h (no extra global IO).
//   Phase C: bilinear gather = LDS b128 reads (8-cy floor); rare (|oy|>=1,
//            ~1.2% lanes) exec-masked global fallback keeps full correctness.
//   Phase D: 64x64x256 GEMM on mfma_f32_16x16x32_f16 (r3-proven mapping).
// LDS = 96 KB stage + 32 KB S^T (time-shared with partials/pw/pi) = 128 KB
// -> 1 block/CU, 8 waves. All heavy traffic is coalesced streams or LDS.
// ============================================================================
__global__ __launch_bounds__(512, 2) void dcn_fused(
    const float* __restrict__ x,
    const float* __restrict__ w_conv,
    const float* __restrict__ w_off,
    const float* __restrict__ b_off,
    const float* __restrict__ w_mask,
    const float* __restrict__ b_mask,
    float* __restrict__ out)
{
    const int g   = blockIdx.x;
    // XCD swizzle: one image per XCD -> staged-row re-reads (h-1,h,h+1) are
    // L2-hot across neighboring blocks on the same XCD.
    const int row = (g & 7) * (B_ * H_ / 8) + (g >> 3);
    const int b   = row >> 8;
    const int h   = row & (H_ - 1);
    const int t   = threadIdx.x;

    __shared__ uint4 st[3 * 256 * 8];   // 96 KB: [r][px][chunk] 8ch fp16/chunk
    __shared__ uint4 stt[256 * 8];      // 32 KB: S^T later; part/pw/pi early

    float4* part = (float4*)stt;          // [2][256]  (8 KB)
    float4* pw_s = (float4*)(stt + 512);  // [256]     (4 KB)
    int4*   pi_s = (int4*)(stt + 768);    // [256]     (4 KB)

    // ---- Phase A: stage 3 clamped rows, all channels, fp16, swizzled ----
    // unit = (r, channel-pair c2, 16-px group). Writes are 4B h2v, 2-way
    // bank aliasing at worst (free).
#pragma unroll
    for (int k = 0; k < 3; ++k) {
        const int u   = k * 512 + t;
        const int r   = u >> 9;           // staged row slot 0..2
        const int rem = u & 511;
        const int c2  = rem & 31;         // channel pair (c = 2*c2)
        const int g16 = rem >> 5;         // 16-px group
        const int yR  = min(max(h - 1 + r, 0), H_ - 1);
        const float* __restrict__ s0 =
            x + ((size_t)(b * C_ + 2 * c2)) * HW_ + yR * W_ + g16 * 16;
        const float* __restrict__ s1 = s0 + HW_;
        float4 v0[4], v1[4];
#pragma unroll
        for (int q = 0; q < 4; ++q) {
            v0[q] = ((const float4*)s0)[q];
            v1[q] = ((const float4*)s1)[q];
        }
        const int j  = c2 >> 2;           // chunk 0..7 (8 ch per chunk)
        const int pr = c2 & 3;            // pair-in-chunk
#pragma unroll
        for (int q = 0; q < 4; ++q) {
#pragma unroll
            for (int e = 0; e < 4; ++e) {
                const int pxw = g16 * 16 + q * 4 + e;
                h2v pk;
                pk[0] = (_Float16)((const float*)&v0[q])[e];
                pk[1] = (_Float16)((const float*)&v1[q])[e];
                *(h2v*)((char*)st
                        + (size_t)((r * 256 + pxw) * 8 + (j ^ swz(pxw))) * 16
                        + pr * 4) = pk;
            }
        }
    }
    __syncthreads();

    const int px = t & 255;
    const int cg = t >> 8;

    // ---- Phase B: offset/mask logits from staged row h (slot 1) ----
    float oy = 0.f, ox = 0.f, ml = 0.f;
#pragma unroll
    for (int k = 0; k < 4; ++k) {
        const int j = cg * 4 + k;
        union { uint4 u; _Float16 hh[8]; } blk;
        blk.u = st[(256 + px) * 8 + (j ^ swz(px))];
#pragma unroll
        for (int e = 0; e < 8; ++e) {
            const float v = (float)blk.hh[e];
            const int c = j * 8 + e;       // wave-uniform -> s_load weights
            oy = fmaf(w_off[c],      v, oy);
            ox = fmaf(w_off[C_ + c], v, ox);
            ml = fmaf(w_mask[c],     v, ml);
        }
    }
    part[cg * 256 + px] = (float4){oy, ox, ml, 0.f};
    __syncthreads();

    if (cg == 0) {
        const float4 o2 = part[256 + px];
        const float oyf = oy + o2.x + b_off[0];
        const float oxf = ox + o2.y + b_off[1];
        const float mlf = ml + o2.z + b_mask[0];
        const float m = 1.0f / (1.0f + __expf(-mlf));

        const float py  = (float)h + oyf;
        const float pxf = (float)px + oxf;
        const float y0f = floorf(py), x0f = floorf(pxf);
        const float wy1 = py - y0f, wx1 = pxf - x0f;
        const float wy0 = 1.0f - wy1, wx0 = 1.0f - wx1;
        const int y0 = (int)y0f, x0 = (int)x0f;
        const int y1 = y0 + 1,   x1 = x0 + 1;
        const float vy0 = (y0 >= 0 && y0 < H_) ? 1.0f : 0.0f;
        const float vy1 = (y1 >= 0 && y1 < H_) ? 1.0f : 0.0f;
        const float vx0 = (x0 >= 0 && x0 < W_) ? 1.0f : 0.0f;
        const float vx1 = (x1 >= 0 && x1 < W_) ? 1.0f : 0.0f;
        const int x0c = min(max(x0, 0), W_ - 1);
        const int x1c = min(max(x1, 0), W_ - 1);
        pw_s[px] = (float4){wy0 * wx0 * vy0 * vx0 * m,
                            wy0 * wx1 * vy0 * vx1 * m,
                            wy1 * wx0 * vy1 * vx0 * m,
                            wy1 * wx1 * vy1 * vx1 * m};
        pi_s[px] = (int4){y0, x0c, x1c, 0};
    }
    __syncthreads();

    const float4 wv4 = pw_s[px];
    const int4   iv  = pi_s[px];
    __syncthreads();   // pw/pi consumed; stt area free for S^T writes

    // ---- Phase C: bilinear gather from LDS (+ rare global fallback) ----
    {
        const int y0  = iv.x, x0c = iv.y, x1c = iv.z;
        const int sA  = y0 - (h - 1);         // staged slot of row y0
        const int sB  = sA + 1;
        const bool inA = (unsigned)sA <= 2u;
        const bool inB = (unsigned)sB <= 2u;
        const int y0c = min(max(y0, 0), H_ - 1);
        const int y1c = min(max(y0 + 1, 0), H_ - 1);

        h2v W00, W01, W10, W11;
        W00[0] = W00[1] = (_Float16)wv4.x;
        W01[0] = W01[1] = (_Float16)wv4.y;
        W10[0] = W10[1] = (_Float16)wv4.z;
        W11[0] = W11[1] = (_Float16)wv4.w;

        const float* __restrict__ xb = x + (size_t)b * C_ * HW_;
#pragma unroll
        for (int k = 0; k < 4; ++k) {
            const int j = cg * 4 + k;         // global chunk 0..7
            uint4 uA0, uA1, uB0, uB1;
            if (inA) {
                uA0 = st[(sA * 256 + x0c) * 8 + (j ^ swz(x0c))];
                uA1 = st[(sA * 256 + x1c) * 8 + (j ^ swz(x1c))];
            } else {
                const float* p0 = xb + (size_t)(j * 8) * HW_ + y0c * W_;
                union { h2v hp[4]; uint4 u; } t0, t1;
#pragma unroll
                for (int e = 0; e < 4; ++e) {
                    t0.hp[e][0] = (_Float16)p0[(size_t)(2 * e)     * HW_ + x0c];
                    t0.hp[e][1] = (_Float16)p0[(size_t)(2 * e + 1) * HW_ + x0c];
                    t1.hp[e][0] = (_Float16)p0[(size_t)(2 * e)     * HW_ + x1c];
                    t1.hp[e][1] = (_Float16)p0[(size_t)(2 * e + 1) * HW_ + x1c];
                }
                uA0 = t0.u; uA1 = t1.u;
            }
            if (inB) {
                uB0 = st[(sB * 256 + x0c) * 8 + (j ^ swz(x0c))];
                uB1 = st[(sB * 256 + x1c) * 8 + (j ^ swz(x1c))];
            } else {
                const float* p1 = xb + (size_t)(j * 8) * HW_ + y1c * W_;
                union { h2v hp[4]; uint4 u; } t0, t1;
#pragma unroll
                for (int e = 0; e < 4; ++e) {
                    t0.hp[e][0] = (_Float16)p1[(size_t)(2 * e)     * HW_ + x0c];
                    t0.hp[e][1] = (_Float16)p1[(size_t)(2 * e + 1) * HW_ + x0c];
                    t1.hp[e][0] = (_Float16)p1[(size_t)(2 * e)     * HW_ + x1c];
                    t1.hp[e][1] = (_Float16)p1[(size_t)(2 * e + 1) * HW_ + x1c];
                }
                uB0 = t0.u; uB1 = t1.u;
            }
            union { uint4 u; h2v p[4]; } a0, a1, a2, a3, s;
            a0.u = uA0; a1.u = uA1; a2.u = uB0; a3.u = uB1;
#pragma unroll
            for (int w2 = 0; w2 < 4; ++w2)
                s.p[w2] = W00 * a0.p[w2] + W01 * a1.p[w2]
                        + W10 * a2.p[w2] + W11 * a3.p[w2];
            stt[px * 8 + (j ^ swz(px))] = s.u;
        }
    }

    // ---- Phase D setup: A fragments (w_conv f32->f16, L2-hot) ----
    const int lane = t & 63;
    const int wv_  = t >> 6;
    const int half = wv_ >> 2;               // 32-oc half owned by this wave
    const int wq   = wv_ & 3;                // 64-px quarter
    const int lrow = lane >> 4;
    const int lcol = lane & 15;

    h8v afrag[2][2];
#pragma unroll
    for (int mtl = 0; mtl < 2; ++mtl) {
#pragma unroll
        for (int kk = 0; kk < 2; ++kk) {
            const int oc = (half * 2 + mtl) * 16 + lcol;
            const int c0 = kk * 32 + lrow * 8;
            const float4* wp = (const float4*)(w_conv + oc * C_ + c0);
            const float4 lo = wp[0];
            const float4 hi = wp[1];
            h8v a;
            a[0] = (_Float16)lo.x; a[1] = (_Float16)lo.y;
            a[2] = (_Float16)lo.z; a[3] = (_Float16)lo.w;
            a[4] = (_Float16)hi.x; a[5] = (_Float16)hi.y;
            a[6] = (_Float16)hi.z; a[7] = (_Float16)hi.w;
            afrag[mtl][kk] = a;
        }
    }

    __syncthreads();

    // ---- Phase D: GEMM via mfma_f32_16x16x32_f16 ----
    f32x4 acc[2][4];
#pragma unroll
    for (int mtl = 0; mtl < 2; ++mtl)
#pragma unroll
        for (int nt = 0; nt < 4; ++nt)
            acc[mtl][nt] = (f32x4){0.f, 0.f, 0.f, 0.f};

#pragma unroll
    for (int nt = 0; nt < 4; ++nt) {
        const int p2 = wq * 64 + nt * 16 + lcol;     // B: n = lcol
#pragma unroll
        for (int kk = 0; kk < 2; ++kk) {
            const int cblk = kk * 4 + lrow;          // B: k = lrow*8+j
            union { uint4 u; h8v v; } bb;
            bb.u = stt[p2 * 8 + (cblk ^ swz(p2))];
#pragma unroll
            for (int mtl = 0; mtl < 2; ++mtl)
                acc[mtl][nt] = __builtin_amdgcn_mfma_f32_16x16x32_f16(
                    afrag[mtl][kk], bb.v, acc[mtl][nt], 0, 0, 0);
        }
    }

    // ---- Epilogue: C/D layout col=lane&15, row=(lane>>4)*4+r ----
    float* __restrict__ ob = out + (size_t)b * OC_ * HW_ + h * W_;
#pragma unroll
    for (int mtl = 0; mtl < 2; ++mtl) {
        const int ocb = (half * 2 + mtl) * 16 + lrow * 4;
#pragma unroll
        for (int nt = 0; nt < 4; ++nt) {
            const int p2 = wq * 64 + nt * 16 + lcol;
            const f32x4 a = acc[mtl][nt];
#pragma unroll
            for (int r = 0; r < 4; ++r)
                ob[(size_t)(ocb + r) * HW_ + p2] = a[r];
        }
    }
}

extern "C" void kernel_launch(void* const* d_in, const int* in_sizes, int n_in,
                              void* d_out, int out_size, void* d_ws, size_t ws_size,
                              hipStream_t stream) {
    const float* x      = (const float*)d_in[0];
    const float* w_conv = (const float*)d_in[1];
    const float* w_off  = (const float*)d_in[2];
    const float* b_off  = (const float*)d_in[3];
    const float* w_mask = (const float*)d_in[4];
    const float* b_mask = (const float*)d_in[5];
    float* out = (float*)d_out;

    // No d_ws use: avoids the harness's 512 MiB per-iteration poison fill.
    dcn_fused<<<dim3(B_ * H_), dim3(512), 0, stream>>>(
        x, w_conv, w_off, b_off, w_mask, b_mask, out);
}

// Round 5
// 293.702 us; speedup vs baseline: 1.1670x; 1.0233x over previous
//
#include <hip/hip_runtime.h>

#define B_  8
#define C_  64
#define OC_ 64
#define H_  256
#define W_  256
#define HW_ (H_ * W_)

typedef __attribute__((ext_vector_type(4))) float f32x4;
typedef _Float16 h2v __attribute__((ext_vector_type(2)));  // packed fp16 pair
typedef _Float16 h8v __attribute__((ext_vector_type(8)));  // MFMA f16 A/B frag

// chunk-slot swizzle: spreads the 8 16B channel-chunks of a pixel across
// banks keyed by pixel, bijective per px (XOR involution).
__device__ __forceinline__ int swz(int p) { return (p ^ (p >> 3)) & 7; }

// ============================================================================
// Round-7: same 128 KB LDS structure as round-6 (proven: 163->136 us), but
// 1024 threads/block. Diagnosis: round-6 was occupancy-capped (1 block/CU x
// 8 waves, Occ 20.8%) with a 5-barrier serial phase chain -> 17 us/block vs
// ~7 us of throughput work. Doubling in-block waves halves each thread's
// serial chain AND doubles latency-hiding waves (16/CU):
//   Phase A: stage rows clamp(h-1..h+1) x 64ch fp16 (grid-stride, 1536 units)
//   Phase B: offset/mask dot, 4 threads/px x 16ch, LDS reduce
//   Phase C: bilinear gather from LDS, 4 threads/px x 2 chunks
//   Phase D: GEMM on mfma_f32_16x16x32_f16, 16 waves x (16oc x 64px) tiles
// ============================================================================
__global__ __launch_bounds__(1024, 4) void dcn_fused(
    const float* __restrict__ x,
    const float* __restrict__ w_conv,
    const float* __restrict__ w_off,
    const float* __restrict__ b_off,
    const float* __restrict__ w_mask,
    const float* __restrict__ b_mask,
    float* __restrict__ out)
{
    const int g   = blockIdx.x;
    // XCD swizzle: one image per XCD -> staged-row re-reads L2-hot.
    const int row = (g & 7) * (B_ * H_ / 8) + (g >> 3);
    const int b   = row >> 8;
    const int h   = row & (H_ - 1);
    const int t   = threadIdx.x;

    __shared__ uint4 st[3 * 256 * 8];   // 96 KB: [r][px][chunk] 8ch fp16/chunk
    __shared__ uint4 stt[256 * 8];      // 32 KB: S^T later; part/pw/pi early

    float4* part = (float4*)stt;           // [4][256] 16 KB
    float4* pw_s = (float4*)(stt + 1024);  // [256]     4 KB
    int4*   pi_s = (int4*)(stt + 1280);    // [256]     4 KB

    // ---- Phase A: stage 3 clamped rows, all channels, fp16, swizzled ----
    // 1536 units = 3 rows x 32 ch-pairs x 16 px-groups; grid-stride.
    for (int u = t; u < 1536; u += 1024) {
        const int r   = u >> 9;           // staged row slot 0..2
        const int rem = u & 511;
        const int c2  = rem & 31;         // channel pair (c = 2*c2)
        const int g16 = rem >> 5;         // 16-px group
        const int yR  = min(max(h - 1 + r, 0), H_ - 1);
        const float* __restrict__ s0 =
            x + ((size_t)(b * C_ + 2 * c2)) * HW_ + yR * W_ + g16 * 16;
        const float* __restrict__ s1 = s0 + HW_;
        float4 v0[4], v1[4];
#pragma unroll
        for (int q = 0; q < 4; ++q) {
            v0[q] = ((const float4*)s0)[q];
            v1[q] = ((const float4*)s1)[q];
        }
        const int j  = c2 >> 2;           // chunk 0..7 (8 ch per chunk)
        const int pr = c2 & 3;            // pair-in-chunk
#pragma unroll
        for (int q = 0; q < 4; ++q) {
#pragma unroll
            for (int e = 0; e < 4; ++e) {
                const int pxw = g16 * 16 + q * 4 + e;
                h2v pk;
                pk[0] = (_Float16)((const float*)&v0[q])[e];
                pk[1] = (_Float16)((const float*)&v1[q])[e];
                *(h2v*)((char*)st
                        + (size_t)((r * 256 + pxw) * 8 + (j ^ swz(pxw))) * 16
                        + pr * 4) = pk;
            }
        }
    }
    __syncthreads();

    const int px = t & 255;
    const int cq = t >> 8;                // 0..3: 16-ch quarter

    // ---- Phase B: offset/mask logits from staged row h (slot 1) ----
    {
        float oy = 0.f, ox = 0.f, ml = 0.f;
#pragma unroll
        for (int k = 0; k < 2; ++k) {
            const int j = cq * 2 + k;
            union { uint4 u; _Float16 hh[8]; } blk;
            blk.u = st[(256 + px) * 8 + (j ^ swz(px))];
#pragma unroll
            for (int e = 0; e < 8; ++e) {
                const float v = (float)blk.hh[e];
                const int c = j * 8 + e;   // wave-uniform -> s_load weights
                oy = fmaf(w_off[c],      v, oy);
                ox = fmaf(w_off[C_ + c], v, ox);
                ml = fmaf(w_mask[c],     v, ml);
            }
        }
        part[cq * 256 + px] = (float4){oy, ox, ml, 0.f};
    }
    __syncthreads();

    if (t < 256) {                         // cq==0 threads finalize
        const float4 p0 = part[t];
        const float4 p1 = part[256 + t];
        const float4 p2 = part[512 + t];
        const float4 p3 = part[768 + t];
        const float oyf = p0.x + p1.x + p2.x + p3.x + b_off[0];
        const float oxf = p0.y + p1.y + p2.y + p3.y + b_off[1];
        const float mlf = p0.z + p1.z + p2.z + p3.z + b_mask[0];
        const float m = 1.0f / (1.0f + __expf(-mlf));

        const float py  = (float)h + oyf;
        const float pxf = (float)t + oxf;
        const float y0f = floorf(py), x0f = floorf(pxf);
        const float wy1 = py - y0f, wx1 = pxf - x0f;
        const float wy0 = 1.0f - wy1, wx0 = 1.0f - wx1;
        const int y0 = (int)y0f, x0 = (int)x0f;
        const int y1 = y0 + 1,   x1 = x0 + 1;
        const float vy0 = (y0 >= 0 && y0 < H_) ? 1.0f : 0.0f;
        const float vy1 = (y1 >= 0 && y1 < H_) ? 1.0f : 0.0f;
        const float vx0 = (x0 >= 0 && x0 < W_) ? 1.0f : 0.0f;
        const float vx1 = (x1 >= 0 && x1 < W_) ? 1.0f : 0.0f;
        const int x0c = min(max(x0, 0), W_ - 1);
        const int x1c = min(max(x1, 0), W_ - 1);
        pw_s[t] = (float4){wy0 * wx0 * vy0 * vx0 * m,
                           wy0 * wx1 * vy0 * vx1 * m,
                           wy1 * wx0 * vy1 * vx0 * m,
                           wy1 * wx1 * vy1 * vx1 * m};
        pi_s[t] = (int4){y0, x0c, x1c, 0};
    }
    __syncthreads();

    const float4 wv4 = pw_s[px];
    const int4   iv  = pi_s[px];
    __syncthreads();   // pw/pi consumed; stt area free for S^T writes

    // ---- Phase C: bilinear gather from LDS (+ rare global fallback) ----
    {
        const int y0  = iv.x, x0c = iv.y, x1c = iv.z;
        const int sA  = y0 - (h - 1);         // staged slot of row y0
        const int sB  = sA + 1;
        const bool inA = (unsigned)sA <= 2u;
        const bool inB = (unsigned)sB <= 2u;
        const int y0c = min(max(y0, 0), H_ - 1);
        const int y1c = min(max(y0 + 1, 0), H_ - 1);

        h2v W00, W01, W10, W11;
        W00[0] = W00[1] = (_Float16)wv4.x;
        W01[0] = W01[1] = (_Float16)wv4.y;
        W10[0] = W10[1] = (_Float16)wv4.z;
        W11[0] = W11[1] = (_Float16)wv4.w;

        const float* __restrict__ xb = x + (size_t)b * C_ * HW_;
#pragma unroll
        for (int k = 0; k < 2; ++k) {
            const int j = cq * 2 + k;         // global chunk 0..7
            uint4 uA0, uA1, uB0, uB1;
            if (inA) {
                uA0 = st[(sA * 256 + x0c) * 8 + (j ^ swz(x0c))];
                uA1 = st[(sA * 256 + x1c) * 8 + (j ^ swz(x1c))];
            } else {
                const float* p0 = xb + (size_t)(j * 8) * HW_ + y0c * W_;
                union { h2v hp[4]; uint4 u; } t0, t1;
#pragma unroll
                for (int e = 0; e < 4; ++e) {
                    t0.hp[e][0] = (_Float16)p0[(size_t)(2 * e)     * HW_ + x0c];
                    t0.hp[e][1] = (_Float16)p0[(size_t)(2 * e + 1) * HW_ + x0c];
                    t1.hp[e][0] = (_Float16)p0[(size_t)(2 * e)     * HW_ + x1c];
                    t1.hp[e][1] = (_Float16)p0[(size_t)(2 * e + 1) * HW_ + x1c];
                }
                uA0 = t0.u; uA1 = t1.u;
            }
            if (inB) {
                uB0 = st[(sB * 256 + x0c) * 8 + (j ^ swz(x0c))];
                uB1 = st[(sB * 256 + x1c) * 8 + (j ^ swz(x1c))];
            } else {
                const float* p1 = xb + (size_t)(j * 8) * HW_ + y1c * W_;
                union { h2v hp[4]; uint4 u; } t0, t1;
#pragma unroll
                for (int e = 0; e < 4; ++e) {
                    t0.hp[e][0] = (_Float16)p1[(size_t)(2 * e)     * HW_ + x0c];
                    t0.hp[e][1] = (_Float16)p1[(size_t)(2 * e + 1) * HW_ + x0c];
                    t1.hp[e][0] = (_Float16)p1[(size_t)(2 * e)     * HW_ + x1c];
                    t1.hp[e][1] = (_Float16)p1[(size_t)(2 * e + 1) * HW_ + x1c];
                }
                uB0 = t0.u; uB1 = t1.u;
            }
            union { uint4 u; h2v p[4]; } a0, a1, a2, a3, s;
            a0.u = uA0; a1.u = uA1; a2.u = uB0; a3.u = uB1;
#pragma unroll
            for (int w2 = 0; w2 < 4; ++w2)
                s.p[w2] = W00 * a0.p[w2] + W01 * a1.p[w2]
                        + W10 * a2.p[w2] + W11 * a3.p[w2];
            stt[px * 8 + (j ^ swz(px))] = s.u;
        }
    }

    // ---- Phase D setup: A fragments (w_conv f32->f16, L2-hot) ----
    const int lane = t & 63;
    const int wv_  = t >> 6;                 // 0..15
    const int ocq  = wv_ >> 2;               // 16-oc block owned by this wave
    const int wq   = wv_ & 3;                // 64-px quarter
    const int lrow = lane >> 4;
    const int lcol = lane & 15;

    h8v afrag[2];
#pragma unroll
    for (int kk = 0; kk < 2; ++kk) {
        const int oc = ocq * 16 + lcol;
        const int c0 = kk * 32 + lrow * 8;
        const float4* wp = (const float4*)(w_conv + oc * C_ + c0);
        const float4 lo = wp[0];
        const float4 hi = wp[1];
        h8v a;
        a[0] = (_Float16)lo.x; a[1] = (_Float16)lo.y;
        a[2] = (_Float16)lo.z; a[3] = (_Float16)lo.w;
        a[4] = (_Float16)hi.x; a[5] = (_Float16)hi.y;
        a[6] = (_Float16)hi.z; a[7] = (_Float16)hi.w;
        afrag[kk] = a;
    }

    __syncthreads();

    // ---- Phase D: GEMM via mfma_f32_16x16x32_f16, 8 MFMA per wave ----
    f32x4 acc[4];
#pragma unroll
    for (int nt = 0; nt < 4; ++nt)
        acc[nt] = (f32x4){0.f, 0.f, 0.f, 0.f};

#pragma unroll
    for (int nt = 0; nt < 4; ++nt) {
        const int p2 = wq * 64 + nt * 16 + lcol;     // B: n = lcol
#pragma unroll
        for (int kk = 0; kk < 2; ++kk) {
            const int cblk = kk * 4 + lrow;          // B: k = lrow*8+j
            union { uint4 u; h8v v; } bb;
            bb.u = stt[p2 * 8 + (cblk ^ swz(p2))];
            acc[nt] = __builtin_amdgcn_mfma_f32_16x16x32_f16(
                afrag[kk], bb.v, acc[nt], 0, 0, 0);
        }
    }

    // ---- Epilogue: C/D layout col=lane&15, row=(lane>>4)*4+r ----
    float* __restrict__ ob = out + (size_t)b * OC_ * HW_ + h * W_;
    const int ocb = ocq * 16 + lrow * 4;
#pragma unroll
    for (int nt = 0; nt < 4; ++nt) {
        const int p2 = wq * 64 + nt * 16 + lcol;
        const f32x4 a = acc[nt];
#pragma unroll
        for (int r = 0; r < 4; ++r)
            ob[(size_t)(ocb + r) * HW_ + p2] = a[r];
    }
}

extern "C" void kernel_launch(void* const* d_in, const int* in_sizes, int n_in,
                              void* d_out, int out_size, void* d_ws, size_t ws_size,
                              hipStream_t stream) {
    const float* x      = (const float*)d_in[0];
    const float* w_conv = (const float*)d_in[1];
    const float* w_off  = (const float*)d_in[2];
    const float* b_off  = (const float*)d_in[3];
    const float* w_mask = (const float*)d_in[4];
    const float* b_mask = (const float*)d_in[5];
    float* out = (float*)d_out;

    // No d_ws use: avoids the harness's 512 MiB per-iteration poison fill.
    dcn_fused<<<dim3(B_ * H_), dim3(1024), 0, stream>>>(
        x, w_conv, w_off, b_off, w_mask, b_mask, out);
}